// Round 13
// baseline (166.998 us; speedup 1.0000x reference)
//
#include <hip/hip_runtime.h>

// BiAttention: B=16, M=N=512, V=A=1024. fp16 MFMA pipeline.
// Deep-pipelined GEMMs on a bank-conflict-free XOR-swizzled global layout:
//   fp16 tiles of 128 rows x 32 k, elem (r,k) at
//     tile*4096 + (r&127)*32 + ((((k>>3)&3) ^ ((r>>1)&3))<<3) + (k&7)
//
// Round 13:
//  - scores GEMM: BK=64, 3-deep circular buffer (96 KiB LDS), counted
//    vmcnt(8) (prefetch distance 2, never drains) -> sync walls halved.
//  - gemm256: stage issued right after the barrier (before frag ds_reads).
//  Proj schedule frozen: 5 schedule families all pinned ~30% MfmaUtil = the
//  m97-family ceiling; remaining wins are sync-count + traffic.
//
//   s_q = relu(q @ W1^T), s_p = relu(p @ W2^T)   [gemm256_dp<true,2>]
//   s   = s_q @ s_p^T (batched, 1-term)          [gemm_dp64, 128^2, swapped]
//   wp  = softmax_n(s), wq = softmax_m(s^T)      [row + column softmax]
//   out_q = wp @ p, out_p = wq @ q               [gemm256_dp<false,1>, swapped]
//
// Workspace (84 MiB), liveness-ordered:
//   [0,4)  W1h|W2h                    (dead after proj)
//   [4,20) qh   [20,36) ph            (alive until prep_xT2)
//   [36,52) sqh [52,68) sph           (dead after scores)
//   [68,84) s fp32                    (written by scores)
//   after scores:  pT [36,52) qT [52,68)  (prep_xT2, over sqh/sph)
//   after prep_xT2: wp [4,12) wq [12,20)  (softmaxes, over qh)

#define AS1 __attribute__((address_space(1)))
#define AS3 __attribute__((address_space(3)))

typedef _Float16 f16x8 __attribute__((ext_vector_type(8)));
typedef _Float16 f16x4 __attribute__((ext_vector_type(4)));
typedef float f32x4 __attribute__((ext_vector_type(4)));

// swizzled element offset inside the tiled fp16 layout (k-tiles of 32)
__device__ __forceinline__ long tswz(int r, int k, int ktiles) {
  return ((long)((r >> 7) * ktiles + (k >> 5)) << 12)
       + ((long)(r & 127) << 5)
       + ((((k >> 3) & 3) ^ ((r >> 1) & 3)) << 3) + (k & 7);
}

// ---- fp32 -> fp16 swizzled tiles: q rows, p rows, then W1|W2 rows ---------
__global__ __launch_bounds__(256) void prep_all(
    const float* __restrict__ q, const float* __restrict__ p,
    const float* __restrict__ W1, const float* __restrict__ W2,
    _Float16* __restrict__ xdst, _Float16* __restrict__ wdst)
{
  long g = (long)blockIdx.x * 256 + threadIdx.x;   // one thread per 8 elems
  int rg = (int)(g >> 7);
  int c8 = ((int)g & 127) << 3;
  const float* srow;
  _Float16* dst;
  long off;
  if (rg < 8192) {
    srow = q + (long)rg * 1024 + c8; dst = xdst; off = tswz(rg, c8, 32);
  } else if (rg < 16384) {
    srow = p + (long)(rg - 8192) * 1024 + c8; dst = xdst; off = tswz(rg, c8, 32);
  } else {
    int r2 = rg - 16384;
    srow = (r2 < 1024 ? W1 + (long)r2 * 1024 : W2 + (long)(r2 - 1024) * 1024) + c8;
    dst = wdst; off = tswz(r2, c8, 32);
  }
  const float4* s4 = (const float4*)srow;
  float4 f0 = s4[0], f1 = s4[1];
  f16x8 hh;
  hh[0]=(_Float16)f0.x; hh[1]=(_Float16)f0.y; hh[2]=(_Float16)f0.z; hh[3]=(_Float16)f0.w;
  hh[4]=(_Float16)f1.x; hh[5]=(_Float16)f1.y; hh[6]=(_Float16)f1.z; hh[7]=(_Float16)f1.w;
  *(f16x8*)(dst + off) = hh;
}

// ---- fp16 tiles -> transposed fp16 tiles: p->pT then q->qT (no re-round) --
__global__ __launch_bounds__(256) void prep_xT2(
    const _Float16* __restrict__ xh, _Float16* __restrict__ dstT)
{
  __shared__ _Float16 t[64][72];
  const int x = blockIdx.x, y = blockIdx.y, zz = blockIdx.z;
  const int rbase = (zz < 16) ? (8192 + zz * 512) : ((zz - 16) * 512);
  const int tid = threadIdx.x;
  for (int it = 0; it < 2; ++it) {
    int id = it * 256 + tid;            // 512 units of 8 elems
    int mloc = id >> 3, v8 = (id & 7) << 3;
    f16x8 v = *(const f16x8*)(xh + tswz(rbase + y * 64 + mloc, x * 64 + v8, 32));
    *(f16x8*)(&t[mloc][v8]) = v;
  }
  __syncthreads();
  _Float16* db = dstT + (long)zz * 524288;
  for (int it = 0; it < 2; ++it) {
    int id = it * 256 + tid;
    int c = id >> 3, ch = id & 7;       // c: v-local, ch: m-octet
    int v = x * 64 + c, mb = y * 64 + ch * 8;
    f16x8 hh;
#pragma unroll
    for (int i = 0; i < 8; ++i) hh[i] = t[ch * 8 + i][c];
    *(f16x8*)(db + tswz(v, mb, 16)) = hh;
  }
}

// ---- 256^2 deep-pipelined NT GEMM, 8 waves, wave tile 128x64 --------------
// All MFMAs SWAPPED: acc[mi][ni] = mfma(fb[ni], fa[mi]).
// OUTMODE 1: fp32 row-major, f32x4 stores (cSplit batch offsets).
// OUTMODE 2: fp16 swizzled tiles, f16x4 stores (projections, RELU).
template<bool RELU, int OUTMODE>
__global__ __launch_bounds__(512, 2) void gemm256_dp(
    const _Float16* __restrict__ A, const _Float16* __restrict__ B,
    float* __restrict__ Cf, _Float16* __restrict__ Ch,
    const int ktiles, const int ldc,
    const long aBatchTiles, const long bBatchTiles, const long cBatchElems,
    const int cTilesRow, const long cOff0, const long cOff1, const int cSplit)
{
  __shared__ _Float16 sA[4][8192];   // 256 rows x 32 k per buf (16 KB)
  __shared__ _Float16 sB[4][8192];

  const int gx = gridDim.x, gy = gridDim.y;
  long nwg = (long)gx * gy * gridDim.z;
  long bid = blockIdx.x + (long)gx * (blockIdx.y + (long)gy * blockIdx.z);
  long chunk = nwg >> 3;
  long o = (bid & 7) * chunk + (bid >> 3);
  const int bx = (int)(o % gx);
  const int by = (int)((o / gx) % gy);
  const int bz = (int)(o / ((long)gx * gy));

  const int tid = threadIdx.x;
  const int lane = tid & 63, w = tid >> 6;
  const int wm = w >> 2, wn = w & 3;            // 2 x 4 wave grid, 128x64/wave
  const int lrow = lane & 15, kg = lane >> 4;
  const int swz = (lrow >> 1) & 3;              // read-side XOR slot swizzle

  const long aT0 = (long)bz * aBatchTiles + (long)(2 * by) * ktiles;
  const long bT0 = (long)bz * bBatchTiles + (long)(2 * bx) * ktiles;
  const int NKT = ktiles;

  auto stage = [&](int kt) {
    const int buf = kt & 3;
#pragma unroll
    for (int h = 0; h < 2; ++h) {
      __builtin_amdgcn_global_load_lds(
          (const AS1 void*)(A + ((aT0 + h * ktiles + kt) << 12) + w * 512 + lane * 8),
          (AS3 void*)(&sA[buf][h * 4096 + w * 512]), 16, 0, 0);
      __builtin_amdgcn_global_load_lds(
          (const AS1 void*)(B + ((bT0 + h * ktiles + kt) << 12) + w * 512 + lane * 8),
          (AS3 void*)(&sB[buf][h * 4096 + w * 512]), 16, 0, 0);
    }
  };

  const char* aF = (const char*)&sA[0][0] + wm * 8192 + lrow * 64 + ((kg ^ swz) << 4);
  const char* bF = (const char*)&sB[0][0] + (wn >> 1) * 8192
                 + ((wn & 1) * 64 + lrow) * 64 + ((kg ^ swz) << 4);

  f32x4 acc[8][4] = {};

  stage(0); stage(1); stage(2);

  for (int kt = 0; kt < NKT; ++kt) {
    if (kt < NKT - 2)       asm volatile("s_waitcnt vmcnt(8)" ::: "memory");
    else if (kt == NKT - 2) asm volatile("s_waitcnt vmcnt(4)" ::: "memory");
    else                    asm volatile("s_waitcnt vmcnt(0)" ::: "memory");
    __builtin_amdgcn_s_barrier();
    __builtin_amdgcn_sched_barrier(0);
    if (kt + 3 < NKT) stage(kt + 3);          // issue-early (T3 recipe)
    const int bo = (kt & 3) * 16384;
    f16x8 fa[8], fb[4];
#pragma unroll
    for (int i = 0; i < 8; ++i) fa[i] = *(const f16x8*)(aF + bo + i * 1024);
#pragma unroll
    for (int i = 0; i < 4; ++i) fb[i] = *(const f16x8*)(bF + bo + i * 1024);
    __builtin_amdgcn_s_setprio(1);
#pragma unroll
    for (int mi = 0; mi < 8; ++mi)
#pragma unroll
      for (int ni = 0; ni < 4; ++ni)
        acc[mi][ni] = __builtin_amdgcn_mfma_f32_16x16x32_f16(fb[ni], fa[mi], acc[mi][ni], 0, 0, 0);
    __builtin_amdgcn_s_setprio(0);
  }

  const int m0 = by * 256 + wm * 128 + lrow;        // D col = lane&15
  const int b0 = bx * 256 + wn * 64 + (kg << 2);    // D row = kg*4 + r2
  if (OUTMODE == 1) {
    long cbase = cSplit ? (bz < 16 ? cOff0 + (long)bz * cBatchElems
                                   : cOff1 + (long)(bz - 16) * cBatchElems)
                        : (long)bz * cBatchElems;
    float* Cb = Cf + cbase;
#pragma unroll
    for (int mi = 0; mi < 8; ++mi)
#pragma unroll
      for (int ni = 0; ni < 4; ++ni)
        *(f32x4*)(Cb + (long)(m0 + mi * 16) * ldc + b0 + ni * 16) = acc[mi][ni];
  } else {
    _Float16* Cb = Ch + (long)bz * cBatchElems;
#pragma unroll
    for (int mi = 0; mi < 8; ++mi)
#pragma unroll
      for (int ni = 0; ni < 4; ++ni) {
        f16x4 hv;
#pragma unroll
        for (int r2 = 0; r2 < 4; ++r2) {
          float x = acc[mi][ni][r2];
          if (RELU) x = fmaxf(x, 0.0f);
          hv[r2] = (_Float16)x;
        }
        *(f16x4*)(Cb + tswz(m0 + mi * 16, b0 + ni * 16, cTilesRow)) = hv;
      }
  }
}

// ---- 128^2 scores GEMM: BK=64, 3-deep buffer, counted vmcnt(8) ------------
// Swapped MFMA, f32x4 epilogue. ktiles32 = K/32 (even).
__global__ __launch_bounds__(256, 2) void gemm_dp64(
    const _Float16* __restrict__ Ah, const _Float16* __restrict__ B,
    float* __restrict__ Cf,
    const int ktiles32, const int ldc,
    const long aBatchTiles, const long bBatchTiles, const long cBatchElems)
{
  __shared__ _Float16 sA[3][8192];   // 3 bufs x (2 sub-chunks x 128r x 32k)
  __shared__ _Float16 sB[3][8192];

  const int gx = gridDim.x, gy = gridDim.y;
  long nwg = (long)gx * gy * gridDim.z;
  long bid = blockIdx.x + (long)gx * (blockIdx.y + (long)gy * blockIdx.z);
  long chunk = nwg >> 3;
  long o = (bid & 7) * chunk + (bid >> 3);
  const int bx = (int)(o % gx);
  const int by = (int)((o / gx) % gy);
  const int bz = (int)(o / ((long)gx * gy));

  const int tid = threadIdx.x;
  const int lane = tid & 63, w = tid >> 6;
  const int wa = w >> 1, wb = w & 1;           // 2 x 2 wave grid, 64x64/wave
  const int lrow = lane & 15, kg = lane >> 4;
  const int swz = (lrow >> 1) & 3;

  const long aT0 = (long)bz * aBatchTiles + (long)by * ktiles32;
  const long bT0 = (long)bz * bBatchTiles + (long)bx * ktiles32;
  const int NKT = ktiles32 >> 1;               // BK=64 steps

  auto stage = [&](int kt) {
    const int buf = kt % 3;
#pragma unroll
    for (int j = 0; j < 2; ++j) {              // sub k32-tile
      const long ta = (aT0 + 2 * kt + j) << 12;
      const long tb = (bT0 + 2 * kt + j) << 12;
#pragma unroll
      for (int l = 0; l < 2; ++l) {
        __builtin_amdgcn_global_load_lds(
            (const AS1 void*)(Ah + ta + (l * 256 + tid) * 8),
            (AS3 void*)(&sA[buf][j * 4096 + (l * 256 + tid) * 8]), 16, 0, 0);
        __builtin_amdgcn_global_load_lds(
            (const AS1 void*)(B + tb + (l * 256 + tid) * 8),
            (AS3 void*)(&sB[buf][j * 4096 + (l * 256 + tid) * 8]), 16, 0, 0);
      }
    }
  };

  const char* aF = (const char*)&sA[0][0] + (wa * 64 + lrow) * 64 + ((kg ^ swz) << 4);
  const char* bF = (const char*)&sB[0][0] + (wb * 64 + lrow) * 64 + ((kg ^ swz) << 4);

  f32x4 acc[4][4] = {};

  stage(0); stage(1);

  for (int kt = 0; kt < NKT; ++kt) {
    if (kt < NKT - 1) asm volatile("s_waitcnt vmcnt(8)" ::: "memory");
    else              asm volatile("s_waitcnt vmcnt(0)" ::: "memory");
    __builtin_amdgcn_s_barrier();
    __builtin_amdgcn_sched_barrier(0);
    if (kt + 2 < NKT) stage(kt + 2);
    const int bo = (kt % 3) * 16384;
#pragma unroll
    for (int sub = 0; sub < 2; ++sub) {
      f16x8 fa[4], fb[4];
#pragma unroll
      for (int i = 0; i < 4; ++i) fa[i] = *(const f16x8*)(aF + bo + sub * 8192 + i * 1024);
#pragma unroll
      for (int i = 0; i < 4; ++i) fb[i] = *(const f16x8*)(bF + bo + sub * 8192 + i * 1024);
      __builtin_amdgcn_s_setprio(1);
#pragma unroll
      for (int mi = 0; mi < 4; ++mi)
#pragma unroll
        for (int ni = 0; ni < 4; ++ni)
          acc[mi][ni] = __builtin_amdgcn_mfma_f32_16x16x32_f16(fb[ni], fa[mi], acc[mi][ni], 0, 0, 0);
      __builtin_amdgcn_s_setprio(0);
    }
  }

  float* Cb = Cf + (long)bz * cBatchElems;
  const int m0 = by * 128 + wa * 64 + lrow;         // D col
  const int n0 = bx * 128 + wb * 64 + (kg << 2);    // D row (4 consecutive n)
#pragma unroll
  for (int mi = 0; mi < 4; ++mi)
#pragma unroll
    for (int ni = 0; ni < 4; ++ni)
      *(f32x4*)(Cb + (long)(m0 + mi * 16) * ldc + n0 + ni * 16) = acc[mi][ni];
}

// ---- row softmax (512 cols) -> fp16 swizzled-tile wp ----------------------
__global__ __launch_bounds__(256) void softmax_row(
    const float* __restrict__ S, const int* __restrict__ mask, _Float16* __restrict__ W)
{
  const int row = blockIdx.x, b = row >> 9, m = row & 511;
  const float* Sr = S + (long)row * 512;
  const int* mr = mask + (long)b * 512;
  const int tid = threadIdx.x;
  const int lane = tid & 63, wave = tid >> 6;
  __shared__ float red[4];

  float v0 = mr[tid] ? Sr[tid] : -1e30f;
  float v1 = mr[tid + 256] ? Sr[tid + 256] : -1e30f;
  float mx = fmaxf(v0, v1);
#pragma unroll
  for (int of = 32; of >= 1; of >>= 1) mx = fmaxf(mx, __shfl_xor(mx, of, 64));
  if (lane == 0) red[wave] = mx;
  __syncthreads();
  mx = fmaxf(fmaxf(red[0], red[1]), fmaxf(red[2], red[3]));
  __syncthreads();
  float e0 = __expf(v0 - mx), e1 = __expf(v1 - mx);
  float sm = e0 + e1;
#pragma unroll
  for (int of = 32; of >= 1; of >>= 1) sm += __shfl_xor(sm, of, 64);
  if (lane == 0) red[wave] = sm;
  __syncthreads();
  float inv = 1.0f / (red[0] + red[1] + red[2] + red[3]);

  _Float16* Wb = W + (long)b * 262144;
  Wb[tswz(m, tid, 16)] = (_Float16)(e0 * inv);
  Wb[tswz(m, tid + 256, 16)] = (_Float16)(e1 * inv);
}

// ---- column softmax: wq[b][n][m] = softmax_m(s[b][m][n]) ------------------
__global__ __launch_bounds__(256) void softmax_col(
    const float* __restrict__ S, const int* __restrict__ mask, _Float16* __restrict__ W)
{
  __shared__ float ldsT[32][513];
  const int n0 = blockIdx.x * 32, b = blockIdx.y;
  const float* Sb = S + (long)b * 262144;
  const int* mr = mask + (long)b * 512;
  const int tid = threadIdx.x;
  const int lane = tid & 63, w = tid >> 6;

  for (int it = 0; it < 64; ++it) {
    int m = it * 8 + (tid >> 5);
    int c = tid & 31;
    float v = mr[m] ? Sb[(long)m * 512 + n0 + c] : -1e30f;
    ldsT[c][m] = v;
  }
  __syncthreads();

  _Float16* Wb = W + (long)b * 262144;
#pragma unroll
  for (int cc = 0; cc < 8; ++cc) {
    int col = w * 8 + cc;
    float v[8];
#pragma unroll
    for (int j = 0; j < 8; ++j) v[j] = ldsT[col][lane + 64 * j];
    float mx = v[0];
#pragma unroll
    for (int j = 1; j < 8; ++j) mx = fmaxf(mx, v[j]);
#pragma unroll
    for (int of = 32; of >= 1; of >>= 1) mx = fmaxf(mx, __shfl_xor(mx, of, 64));
    float e[8], sm = 0.0f;
#pragma unroll
    for (int j = 0; j < 8; ++j) { e[j] = __expf(v[j] - mx); sm += e[j]; }
#pragma unroll
    for (int of = 32; of >= 1; of >>= 1) sm += __shfl_xor(sm, of, 64);
    float inv = 1.0f / sm;
    int n = n0 + col;
#pragma unroll
    for (int j = 0; j < 8; ++j)
      Wb[tswz(n, lane + 64 * j, 16)] = (_Float16)(e[j] * inv);
  }
}

extern "C" void kernel_launch(void* const* d_in, const int* in_sizes, int n_in,
                              void* d_out, int out_size, void* d_ws, size_t ws_size,
                              hipStream_t stream) {
  const float* q = (const float*)d_in[0];
  const float* p = (const float*)d_in[1];
  const int* q_mask = (const int*)d_in[2];
  const int* p_mask = (const int*)d_in[3];
  const float* W1 = (const float*)d_in[4];
  const float* W2 = (const float*)d_in[5];
  float* out = (float*)d_out;   // [out_p | out_q]

  char* ws = (char*)d_ws;
  const size_t MB = 1048576;
  _Float16* W1h = (_Float16*)(ws + 0 * MB);    // W2h contiguous at +2MB
  _Float16* qh  = (_Float16*)(ws + 4 * MB);    // ph contiguous at +16MB
  _Float16* sqh = (_Float16*)(ws + 36 * MB);   // sph contiguous at +16MB
  float*    s   = (float*)(ws + 68 * MB);      // fresh region (qh stays alive)
  _Float16* pT  = (_Float16*)(ws + 36 * MB);   // over sqh/sph after scores
  _Float16* wp  = (_Float16*)(ws + 4 * MB);    // over qh after prep_xT2
  _Float16* wq  = (_Float16*)(ws + 12 * MB);

  dim3 blk(256);

  // 1) fp16 conversions into swizzled tiles (q, p, W1|W2 in one kernel)
  prep_all<<<9216, blk, 0, stream>>>(q, p, W1, W2, qh, W1h);

  // 2) merged projections, 256^2 (z=0: q@W1 -> sqh, z=1: p@W2 -> sph)
  gemm256_dp<true, 2><<<dim3(4, 32, 2), dim3(512), 0, stream>>>(
      qh, W1h, nullptr, sqh,
      /*ktiles=*/32, /*ldc=*/0,
      /*aBatchTiles=*/2048, /*bBatchTiles=*/256, /*cBatchElems=*/8388608L,
      /*cTilesRow=*/32, 0, 0, 0);

  // 3) scores: s[b] = s_q[b] @ s_p[b]^T, BK=64 3-deep, swapped f32x4 epilogue
  gemm_dp64<<<dim3(4, 4, 16), blk, 0, stream>>>(
      sqh, (_Float16*)(ws + 52 * MB), s, /*ktiles32=*/32, /*ldc=*/512,
      /*aBatchTiles=*/128, /*bBatchTiles=*/128, /*cBatchElems=*/262144L);

  // 4) transposed fp16 copies of p, q from the fp16 tiles (over dead sqh/sph)
  prep_xT2<<<dim3(16, 8, 32), blk, 0, stream>>>(qh, pT);

  // 5) softmaxes (write over dead qh region)
  softmax_row<<<8192, blk, 0, stream>>>(s, p_mask, wp);
  softmax_col<<<dim3(16, 16), blk, 0, stream>>>(s, q_mask, wq);

  // 6) merged outputs, 256^2: z<16: out_q = wp@pT^T; z>=16: out_p = wq@qT^T
  gemm256_dp<false, 1><<<dim3(4, 2, 32), dim3(512), 0, stream>>>(
      wp, pT, out, nullptr,
      /*ktiles=*/16, /*ldc=*/1024,
      /*aBatchTiles=*/64, /*bBatchTiles=*/128, /*cBatchElems=*/524288L,
      0, /*cOff0=*/8388608L, /*cOff1=*/0L, /*cSplit=*/1);
}

// Round 14
// 151.494 us; speedup vs baseline: 1.1023x; 1.1023x over previous
//
#include <hip/hip_runtime.h>

// BiAttention: B=16, M=N=512, V=A=1024. fp16 MFMA pipeline.
// Deep-pipelined GEMMs (BK=32, 4-deep LDS circular buffer, counted vmcnt +
// 1 barrier per K-tile, prefetch distance 3) on a bank-conflict-free
// XOR-swizzled global operand layout:
//   fp16 tiles of 128 rows x 32 k, elem (r,k) at
//     tile*4096 + (r&127)*32 + ((((k>>3)&3) ^ ((r>>1)&3))<<3) + (k&7)
//
// Round 14: exact revert to the round-12 best (151.4 us). Round-13's
// stage-early reorder regressed 10 us/dispatch (frag-read->MFMA chain is the
// critical path; stage must issue after the ds_reads). Schedule frozen:
// six variants all pin ~30% MfmaUtil = the 2-barrier-family ceiling.
//
//   s_q = relu(q @ W1^T), s_p = relu(p @ W2^T)   [gemm256_dp<true,2>]
//   s   = s_q @ s_p^T (batched, 1-term)          [gemm_dp, 128^2, swapped]
//   wp  = softmax_n(s), wq = softmax_m(s^T)      [row + column softmax]
//   out_q = wp @ p, out_p = wq @ q               [gemm256_dp<false,1>, swapped]
//
// Workspace (84 MiB), liveness-ordered:
//   [0,4)  W1h|W2h                    (dead after proj)
//   [4,20) qh   [20,36) ph            (alive until prep_xT2)
//   [36,52) sqh [52,68) sph           (dead after scores)
//   [68,84) s fp32                    (written by scores)
//   after scores:  pT [36,52) qT [52,68)  (prep_xT2, over sqh/sph)
//   after prep_xT2: wp [4,12) wq [12,20)  (softmaxes, over qh)

#define AS1 __attribute__((address_space(1)))
#define AS3 __attribute__((address_space(3)))

typedef _Float16 f16x8 __attribute__((ext_vector_type(8)));
typedef _Float16 f16x4 __attribute__((ext_vector_type(4)));
typedef float f32x4 __attribute__((ext_vector_type(4)));

// swizzled element offset inside the tiled fp16 layout (k-tiles of 32)
__device__ __forceinline__ long tswz(int r, int k, int ktiles) {
  return ((long)((r >> 7) * ktiles + (k >> 5)) << 12)
       + ((long)(r & 127) << 5)
       + ((((k >> 3) & 3) ^ ((r >> 1) & 3)) << 3) + (k & 7);
}

// ---- fp32 -> fp16 swizzled tiles: q rows, p rows, then W1|W2 rows ---------
__global__ __launch_bounds__(256) void prep_all(
    const float* __restrict__ q, const float* __restrict__ p,
    const float* __restrict__ W1, const float* __restrict__ W2,
    _Float16* __restrict__ xdst, _Float16* __restrict__ wdst)
{
  long g = (long)blockIdx.x * 256 + threadIdx.x;   // one thread per 8 elems
  int rg = (int)(g >> 7);
  int c8 = ((int)g & 127) << 3;
  const float* srow;
  _Float16* dst;
  long off;
  if (rg < 8192) {
    srow = q + (long)rg * 1024 + c8; dst = xdst; off = tswz(rg, c8, 32);
  } else if (rg < 16384) {
    srow = p + (long)(rg - 8192) * 1024 + c8; dst = xdst; off = tswz(rg, c8, 32);
  } else {
    int r2 = rg - 16384;
    srow = (r2 < 1024 ? W1 + (long)r2 * 1024 : W2 + (long)(r2 - 1024) * 1024) + c8;
    dst = wdst; off = tswz(r2, c8, 32);
  }
  const float4* s4 = (const float4*)srow;
  float4 f0 = s4[0], f1 = s4[1];
  f16x8 hh;
  hh[0]=(_Float16)f0.x; hh[1]=(_Float16)f0.y; hh[2]=(_Float16)f0.z; hh[3]=(_Float16)f0.w;
  hh[4]=(_Float16)f1.x; hh[5]=(_Float16)f1.y; hh[6]=(_Float16)f1.z; hh[7]=(_Float16)f1.w;
  *(f16x8*)(dst + off) = hh;
}

// ---- fp16 tiles -> transposed fp16 tiles: p->pT then q->qT (no re-round) --
__global__ __launch_bounds__(256) void prep_xT2(
    const _Float16* __restrict__ xh, _Float16* __restrict__ dstT)
{
  __shared__ _Float16 t[64][72];
  const int x = blockIdx.x, y = blockIdx.y, zz = blockIdx.z;
  const int rbase = (zz < 16) ? (8192 + zz * 512) : ((zz - 16) * 512);
  const int tid = threadIdx.x;
  for (int it = 0; it < 2; ++it) {
    int id = it * 256 + tid;            // 512 units of 8 elems
    int mloc = id >> 3, v8 = (id & 7) << 3;
    f16x8 v = *(const f16x8*)(xh + tswz(rbase + y * 64 + mloc, x * 64 + v8, 32));
    *(f16x8*)(&t[mloc][v8]) = v;
  }
  __syncthreads();
  _Float16* db = dstT + (long)zz * 524288;
  for (int it = 0; it < 2; ++it) {
    int id = it * 256 + tid;
    int c = id >> 3, ch = id & 7;       // c: v-local, ch: m-octet
    int v = x * 64 + c, mb = y * 64 + ch * 8;
    f16x8 hh;
#pragma unroll
    for (int i = 0; i < 8; ++i) hh[i] = t[ch * 8 + i][c];
    *(f16x8*)(db + tswz(v, mb, 16)) = hh;
  }
}

// ---- 256^2 deep-pipelined NT GEMM, 8 waves, wave tile 128x64 --------------
// All MFMAs SWAPPED: acc[mi][ni] = mfma(fb[ni], fa[mi]) -> D rows = B-rows,
// D cols = A-rows (lane: col=lane&15 -> m, row=(lane>>4)*4+r2 -> b-dim).
// OUTMODE 1: fp32 row-major, f32x4 stores (cSplit batch offsets).
// OUTMODE 2: fp16 swizzled tiles, f16x4 stores (projections, RELU).
template<bool RELU, int OUTMODE>
__global__ __launch_bounds__(512, 2) void gemm256_dp(
    const _Float16* __restrict__ A, const _Float16* __restrict__ B,
    float* __restrict__ Cf, _Float16* __restrict__ Ch,
    const int ktiles, const int ldc,
    const long aBatchTiles, const long bBatchTiles, const long cBatchElems,
    const int cTilesRow, const long cOff0, const long cOff1, const int cSplit)
{
  __shared__ _Float16 sA[4][8192];   // 256 rows x 32 k per buf (16 KB)
  __shared__ _Float16 sB[4][8192];

  const int gx = gridDim.x, gy = gridDim.y;
  long nwg = (long)gx * gy * gridDim.z;
  long bid = blockIdx.x + (long)gx * (blockIdx.y + (long)gy * blockIdx.z);
  long chunk = nwg >> 3;
  long o = (bid & 7) * chunk + (bid >> 3);
  const int bx = (int)(o % gx);
  const int by = (int)((o / gx) % gy);
  const int bz = (int)(o / ((long)gx * gy));

  const int tid = threadIdx.x;
  const int lane = tid & 63, w = tid >> 6;
  const int wm = w >> 2, wn = w & 3;            // 2 x 4 wave grid, 128x64/wave
  const int lrow = lane & 15, kg = lane >> 4;
  const int swz = (lrow >> 1) & 3;              // read-side XOR slot swizzle

  const long aT0 = (long)bz * aBatchTiles + (long)(2 * by) * ktiles;
  const long bT0 = (long)bz * bBatchTiles + (long)(2 * bx) * ktiles;
  const int NKT = ktiles;

  auto stage = [&](int kt) {
    const int buf = kt & 3;
#pragma unroll
    for (int h = 0; h < 2; ++h) {
      __builtin_amdgcn_global_load_lds(
          (const AS1 void*)(A + ((aT0 + h * ktiles + kt) << 12) + w * 512 + lane * 8),
          (AS3 void*)(&sA[buf][h * 4096 + w * 512]), 16, 0, 0);
      __builtin_amdgcn_global_load_lds(
          (const AS1 void*)(B + ((bT0 + h * ktiles + kt) << 12) + w * 512 + lane * 8),
          (AS3 void*)(&sB[buf][h * 4096 + w * 512]), 16, 0, 0);
    }
  };

  const char* aF = (const char*)&sA[0][0] + wm * 8192 + lrow * 64 + ((kg ^ swz) << 4);
  const char* bF = (const char*)&sB[0][0] + (wn >> 1) * 8192
                 + ((wn & 1) * 64 + lrow) * 64 + ((kg ^ swz) << 4);

  f32x4 acc[8][4] = {};

  stage(0); stage(1); stage(2);

  for (int kt = 0; kt < NKT; ++kt) {
    if (kt < NKT - 2)       asm volatile("s_waitcnt vmcnt(8)" ::: "memory");
    else if (kt == NKT - 2) asm volatile("s_waitcnt vmcnt(4)" ::: "memory");
    else                    asm volatile("s_waitcnt vmcnt(0)" ::: "memory");
    __builtin_amdgcn_s_barrier();
    __builtin_amdgcn_sched_barrier(0);
    const int bo = (kt & 3) * 16384;
    f16x8 fa[8], fb[4];
#pragma unroll
    for (int i = 0; i < 8; ++i) fa[i] = *(const f16x8*)(aF + bo + i * 1024);
#pragma unroll
    for (int i = 0; i < 4; ++i) fb[i] = *(const f16x8*)(bF + bo + i * 1024);
    if (kt + 3 < NKT) stage(kt + 3);
    __builtin_amdgcn_s_setprio(1);
#pragma unroll
    for (int mi = 0; mi < 8; ++mi)
#pragma unroll
      for (int ni = 0; ni < 4; ++ni)
        acc[mi][ni] = __builtin_amdgcn_mfma_f32_16x16x32_f16(fb[ni], fa[mi], acc[mi][ni], 0, 0, 0);
    __builtin_amdgcn_s_setprio(0);
  }

  const int m0 = by * 256 + wm * 128 + lrow;        // D col = lane&15
  const int b0 = bx * 256 + wn * 64 + (kg << 2);    // D row = kg*4 + r2
  if (OUTMODE == 1) {
    long cbase = cSplit ? (bz < 16 ? cOff0 + (long)bz * cBatchElems
                                   : cOff1 + (long)(bz - 16) * cBatchElems)
                        : (long)bz * cBatchElems;
    float* Cb = Cf + cbase;
#pragma unroll
    for (int mi = 0; mi < 8; ++mi)
#pragma unroll
      for (int ni = 0; ni < 4; ++ni)
        *(f32x4*)(Cb + (long)(m0 + mi * 16) * ldc + b0 + ni * 16) = acc[mi][ni];
  } else {
    _Float16* Cb = Ch + (long)bz * cBatchElems;
#pragma unroll
    for (int mi = 0; mi < 8; ++mi)
#pragma unroll
      for (int ni = 0; ni < 4; ++ni) {
        f16x4 hv;
#pragma unroll
        for (int r2 = 0; r2 < 4; ++r2) {
          float x = acc[mi][ni][r2];
          if (RELU) x = fmaxf(x, 0.0f);
          hv[r2] = (_Float16)x;
        }
        *(f16x4*)(Cb + tswz(m0 + mi * 16, b0 + ni * 16, cTilesRow)) = hv;
      }
  }
}

// ---- 128^2 deep-pipelined NT GEMM (scores), swapped f32x4 epilogue --------
__global__ __launch_bounds__(256, 2) void gemm_dp(
    const _Float16* __restrict__ Ah, const _Float16* __restrict__ B,
    float* __restrict__ Cf,
    const int ktiles, const int ldc,
    const long aBatchTiles, const long bBatchTiles, const long cBatchElems)
{
  __shared__ _Float16 sA[4][4096];
  __shared__ _Float16 sB[4][4096];

  const int gx = gridDim.x, gy = gridDim.y;
  long nwg = (long)gx * gy * gridDim.z;
  long bid = blockIdx.x + (long)gx * (blockIdx.y + (long)gy * blockIdx.z);
  long chunk = nwg >> 3;
  long o = (bid & 7) * chunk + (bid >> 3);
  const int bx = (int)(o % gx);
  const int by = (int)((o / gx) % gy);
  const int bz = (int)(o / ((long)gx * gy));

  const int tid = threadIdx.x;
  const int lane = tid & 63, w = tid >> 6;
  const int wa = w >> 1, wb = w & 1;
  const int lrow = lane & 15, kg = lane >> 4;
  const int swz = (lrow >> 1) & 3;

  const long aT0 = (long)bz * aBatchTiles + (long)by * ktiles;
  const long bT0 = (long)bz * bBatchTiles + (long)bx * ktiles;
  const int NKT = ktiles;

  auto stage = [&](int kt) {
    const int buf = kt & 3;
    const long ta = (aT0 + kt) << 12;
    const long tb = (bT0 + kt) << 12;
#pragma unroll
    for (int j = 0; j < 2; ++j) {
      __builtin_amdgcn_global_load_lds(
          (const AS1 void*)(Ah + ta + j * 2048 + w * 512 + lane * 8),
          (AS3 void*)(&sA[buf][j * 2048 + w * 512]), 16, 0, 0);
      __builtin_amdgcn_global_load_lds(
          (const AS1 void*)(B + tb + j * 2048 + w * 512 + lane * 8),
          (AS3 void*)(&sB[buf][j * 2048 + w * 512]), 16, 0, 0);
    }
  };

  const char* aF = (const char*)&sA[0][0] + (wa * 64 + lrow) * 64 + ((kg ^ swz) << 4);
  const char* bF = (const char*)&sB[0][0] + (wb * 64 + lrow) * 64 + ((kg ^ swz) << 4);

  f32x4 acc[4][4] = {};

  stage(0); stage(1); stage(2);

  for (int kt = 0; kt < NKT; ++kt) {
    if (kt < NKT - 2)       asm volatile("s_waitcnt vmcnt(8)" ::: "memory");
    else if (kt == NKT - 2) asm volatile("s_waitcnt vmcnt(4)" ::: "memory");
    else                    asm volatile("s_waitcnt vmcnt(0)" ::: "memory");
    __builtin_amdgcn_s_barrier();
    __builtin_amdgcn_sched_barrier(0);
    const int bo = (kt & 3) * 8192;
    f16x8 fa[4], fb[4];
#pragma unroll
    for (int i = 0; i < 4; ++i) fa[i] = *(const f16x8*)(aF + bo + i * 1024);
#pragma unroll
    for (int i = 0; i < 4; ++i) fb[i] = *(const f16x8*)(bF + bo + i * 1024);
    if (kt + 3 < NKT) stage(kt + 3);
    __builtin_amdgcn_s_setprio(1);
#pragma unroll
    for (int mi = 0; mi < 4; ++mi)
#pragma unroll
      for (int ni = 0; ni < 4; ++ni)
        acc[mi][ni] = __builtin_amdgcn_mfma_f32_16x16x32_f16(fb[ni], fa[mi], acc[mi][ni], 0, 0, 0);
    __builtin_amdgcn_s_setprio(0);
  }

  float* Cb = Cf + (long)bz * cBatchElems;
  const int m0 = by * 128 + wa * 64 + lrow;         // D col
  const int n0 = bx * 128 + wb * 64 + (kg << 2);    // D row (4 consecutive n)
#pragma unroll
  for (int mi = 0; mi < 4; ++mi)
#pragma unroll
    for (int ni = 0; ni < 4; ++ni)
      *(f32x4*)(Cb + (long)(m0 + mi * 16) * ldc + n0 + ni * 16) = acc[mi][ni];
}

// ---- row softmax (512 cols) -> fp16 swizzled-tile wp ----------------------
__global__ __launch_bounds__(256) void softmax_row(
    const float* __restrict__ S, const int* __restrict__ mask, _Float16* __restrict__ W)
{
  const int row = blockIdx.x, b = row >> 9, m = row & 511;
  const float* Sr = S + (long)row * 512;
  const int* mr = mask + (long)b * 512;
  const int tid = threadIdx.x;
  const int lane = tid & 63, wave = tid >> 6;
  __shared__ float red[4];

  float v0 = mr[tid] ? Sr[tid] : -1e30f;
  float v1 = mr[tid + 256] ? Sr[tid + 256] : -1e30f;
  float mx = fmaxf(v0, v1);
#pragma unroll
  for (int of = 32; of >= 1; of >>= 1) mx = fmaxf(mx, __shfl_xor(mx, of, 64));
  if (lane == 0) red[wave] = mx;
  __syncthreads();
  mx = fmaxf(fmaxf(red[0], red[1]), fmaxf(red[2], red[3]));
  __syncthreads();
  float e0 = __expf(v0 - mx), e1 = __expf(v1 - mx);
  float sm = e0 + e1;
#pragma unroll
  for (int of = 32; of >= 1; of >>= 1) sm += __shfl_xor(sm, of, 64);
  if (lane == 0) red[wave] = sm;
  __syncthreads();
  float inv = 1.0f / (red[0] + red[1] + red[2] + red[3]);

  _Float16* Wb = W + (long)b * 262144;
  Wb[tswz(m, tid, 16)] = (_Float16)(e0 * inv);
  Wb[tswz(m, tid + 256, 16)] = (_Float16)(e1 * inv);
}

// ---- column softmax: wq[b][n][m] = softmax_m(s[b][m][n]) ------------------
__global__ __launch_bounds__(256) void softmax_col(
    const float* __restrict__ S, const int* __restrict__ mask, _Float16* __restrict__ W)
{
  __shared__ float ldsT[32][513];
  const int n0 = blockIdx.x * 32, b = blockIdx.y;
  const float* Sb = S + (long)b * 262144;
  const int* mr = mask + (long)b * 512;
  const int tid = threadIdx.x;
  const int lane = tid & 63, w = tid >> 6;

  for (int it = 0; it < 64; ++it) {
    int m = it * 8 + (tid >> 5);
    int c = tid & 31;
    float v = mr[m] ? Sb[(long)m * 512 + n0 + c] : -1e30f;
    ldsT[c][m] = v;
  }
  __syncthreads();

  _Float16* Wb = W + (long)b * 262144;
#pragma unroll
  for (int cc = 0; cc < 8; ++cc) {
    int col = w * 8 + cc;
    float v[8];
#pragma unroll
    for (int j = 0; j < 8; ++j) v[j] = ldsT[col][lane + 64 * j];
    float mx = v[0];
#pragma unroll
    for (int j = 1; j < 8; ++j) mx = fmaxf(mx, v[j]);
#pragma unroll
    for (int of = 32; of >= 1; of >>= 1) mx = fmaxf(mx, __shfl_xor(mx, of, 64));
    float e[8], sm = 0.0f;
#pragma unroll
    for (int j = 0; j < 8; ++j) { e[j] = __expf(v[j] - mx); sm += e[j]; }
#pragma unroll
    for (int of = 32; of >= 1; of >>= 1) sm += __shfl_xor(sm, of, 64);
    float inv = 1.0f / sm;
    int n = n0 + col;
#pragma unroll
    for (int j = 0; j < 8; ++j)
      Wb[tswz(n, lane + 64 * j, 16)] = (_Float16)(e[j] * inv);
  }
}

extern "C" void kernel_launch(void* const* d_in, const int* in_sizes, int n_in,
                              void* d_out, int out_size, void* d_ws, size_t ws_size,
                              hipStream_t stream) {
  const float* q = (const float*)d_in[0];
  const float* p = (const float*)d_in[1];
  const int* q_mask = (const int*)d_in[2];
  const int* p_mask = (const int*)d_in[3];
  const float* W1 = (const float*)d_in[4];
  const float* W2 = (const float*)d_in[5];
  float* out = (float*)d_out;   // [out_p | out_q]

  char* ws = (char*)d_ws;
  const size_t MB = 1048576;
  _Float16* W1h = (_Float16*)(ws + 0 * MB);    // W2h contiguous at +2MB
  _Float16* qh  = (_Float16*)(ws + 4 * MB);    // ph contiguous at +16MB
  _Float16* sqh = (_Float16*)(ws + 36 * MB);   // sph contiguous at +16MB
  float*    s   = (float*)(ws + 68 * MB);      // fresh region (qh stays alive)
  _Float16* pT  = (_Float16*)(ws + 36 * MB);   // over sqh/sph after scores
  _Float16* wp  = (_Float16*)(ws + 4 * MB);    // over qh after prep_xT2
  _Float16* wq  = (_Float16*)(ws + 12 * MB);

  dim3 blk(256);

  // 1) fp16 conversions into swizzled tiles (q, p, W1|W2 in one kernel)
  prep_all<<<9216, blk, 0, stream>>>(q, p, W1, W2, qh, W1h);

  // 2) merged projections, 256^2 (z=0: q@W1 -> sqh, z=1: p@W2 -> sph)
  gemm256_dp<true, 2><<<dim3(4, 32, 2), dim3(512), 0, stream>>>(
      qh, W1h, nullptr, sqh,
      /*ktiles=*/32, /*ldc=*/0,
      /*aBatchTiles=*/2048, /*bBatchTiles=*/256, /*cBatchElems=*/8388608L,
      /*cTilesRow=*/32, 0, 0, 0);

  // 3) scores: s[b] = s_q[b] @ s_p[b]^T, 128^2 swapped f32x4 epilogue
  gemm_dp<<<dim3(4, 4, 16), blk, 0, stream>>>(
      sqh, (_Float16*)(ws + 52 * MB), s, /*ktiles=*/32, /*ldc=*/512,
      /*aBatchTiles=*/128, /*bBatchTiles=*/128, /*cBatchElems=*/262144L);

  // 4) transposed fp16 copies of p, q from the fp16 tiles (over dead sqh/sph)
  prep_xT2<<<dim3(16, 8, 32), blk, 0, stream>>>(qh, pT);

  // 5) softmaxes (write over dead qh region)
  softmax_row<<<8192, blk, 0, stream>>>(s, p_mask, wp);
  softmax_col<<<dim3(16, 16), blk, 0, stream>>>(s, q_mask, wq);

  // 6) merged outputs, 256^2: z<16: out_q = wp@pT^T; z>=16: out_p = wq@qT^T
  gemm256_dp<false, 1><<<dim3(4, 2, 32), dim3(512), 0, stream>>>(
      wp, pT, out, nullptr,
      /*ktiles=*/16, /*ldc=*/1024,
      /*aBatchTiles=*/64, /*bBatchTiles=*/128, /*cBatchElems=*/524288L,
      0, /*cOff0=*/8388608L, /*cOff1=*/0L, /*cSplit=*/1);
}

// Round 15
// 128.314 us; speedup vs baseline: 1.3015x; 1.1807x over previous
//
#include <hip/hip_runtime.h>

// BiAttention: B=16, M=N=512, V=A=1024. fp16 MFMA pipeline.
// Deep-pipelined GEMMs (BK=32, 4-deep LDS circular buffer, counted vmcnt +
// 1 barrier per K-tile, prefetch distance 3) on a bank-conflict-free
// XOR-swizzled global operand layout:
//   fp16 tiles of 128 rows x 32 k, elem (r,k) at
//     tile*4096 + (r&127)*32 + ((((k>>3)&3) ^ ((r>>1)&3))<<3) + (k&7)
//
// Round 15: GEMMs frozen at the round-12/14 best (six schedule variants all
// pin ~30% MfmaUtil = the 2-barrier-family ceiling). This round rewrites the
// two softmax kernels, which cost ~38us for ~8us of ideal traffic:
//  - softmax_row: one WAVE per row (grid 2048), float4 loads, full-wave
//    shfl reduce, one f16x8 swizzled store/lane. No LDS, no barriers.
//  - softmax_col: transpose loads vectorized to float4 (16 iters vs 64).
//
//   s_q = relu(q @ W1^T), s_p = relu(p @ W2^T)   [gemm256_dp<true,2>]
//   s   = s_q @ s_p^T (batched, 1-term)          [gemm_dp, 128^2, swapped]
//   wp  = softmax_n(s), wq = softmax_m(s^T)      [row + column softmax]
//   out_q = wp @ p, out_p = wq @ q               [gemm256_dp<false,1>, swapped]
//
// Workspace (84 MiB), liveness-ordered:
//   [0,4)  W1h|W2h                    (dead after proj)
//   [4,20) qh   [20,36) ph            (alive until prep_xT2)
//   [36,52) sqh [52,68) sph           (dead after scores)
//   [68,84) s fp32                    (written by scores)
//   after scores:  pT [36,52) qT [52,68)  (prep_xT2, over sqh/sph)
//   after prep_xT2: wp [4,12) wq [12,20)  (softmaxes, over qh)

#define AS1 __attribute__((address_space(1)))
#define AS3 __attribute__((address_space(3)))

typedef _Float16 f16x8 __attribute__((ext_vector_type(8)));
typedef _Float16 f16x4 __attribute__((ext_vector_type(4)));
typedef float f32x4 __attribute__((ext_vector_type(4)));

// swizzled element offset inside the tiled fp16 layout (k-tiles of 32)
__device__ __forceinline__ long tswz(int r, int k, int ktiles) {
  return ((long)((r >> 7) * ktiles + (k >> 5)) << 12)
       + ((long)(r & 127) << 5)
       + ((((k >> 3) & 3) ^ ((r >> 1) & 3)) << 3) + (k & 7);
}

// ---- fp32 -> fp16 swizzled tiles: q rows, p rows, then W1|W2 rows ---------
__global__ __launch_bounds__(256) void prep_all(
    const float* __restrict__ q, const float* __restrict__ p,
    const float* __restrict__ W1, const float* __restrict__ W2,
    _Float16* __restrict__ xdst, _Float16* __restrict__ wdst)
{
  long g = (long)blockIdx.x * 256 + threadIdx.x;   // one thread per 8 elems
  int rg = (int)(g >> 7);
  int c8 = ((int)g & 127) << 3;
  const float* srow;
  _Float16* dst;
  long off;
  if (rg < 8192) {
    srow = q + (long)rg * 1024 + c8; dst = xdst; off = tswz(rg, c8, 32);
  } else if (rg < 16384) {
    srow = p + (long)(rg - 8192) * 1024 + c8; dst = xdst; off = tswz(rg, c8, 32);
  } else {
    int r2 = rg - 16384;
    srow = (r2 < 1024 ? W1 + (long)r2 * 1024 : W2 + (long)(r2 - 1024) * 1024) + c8;
    dst = wdst; off = tswz(r2, c8, 32);
  }
  const float4* s4 = (const float4*)srow;
  float4 f0 = s4[0], f1 = s4[1];
  f16x8 hh;
  hh[0]=(_Float16)f0.x; hh[1]=(_Float16)f0.y; hh[2]=(_Float16)f0.z; hh[3]=(_Float16)f0.w;
  hh[4]=(_Float16)f1.x; hh[5]=(_Float16)f1.y; hh[6]=(_Float16)f1.z; hh[7]=(_Float16)f1.w;
  *(f16x8*)(dst + off) = hh;
}

// ---- fp16 tiles -> transposed fp16 tiles: p->pT then q->qT (no re-round) --
__global__ __launch_bounds__(256) void prep_xT2(
    const _Float16* __restrict__ xh, _Float16* __restrict__ dstT)
{
  __shared__ _Float16 t[64][72];
  const int x = blockIdx.x, y = blockIdx.y, zz = blockIdx.z;
  const int rbase = (zz < 16) ? (8192 + zz * 512) : ((zz - 16) * 512);
  const int tid = threadIdx.x;
  for (int it = 0; it < 2; ++it) {
    int id = it * 256 + tid;            // 512 units of 8 elems
    int mloc = id >> 3, v8 = (id & 7) << 3;
    f16x8 v = *(const f16x8*)(xh + tswz(rbase + y * 64 + mloc, x * 64 + v8, 32));
    *(f16x8*)(&t[mloc][v8]) = v;
  }
  __syncthreads();
  _Float16* db = dstT + (long)zz * 524288;
  for (int it = 0; it < 2; ++it) {
    int id = it * 256 + tid;
    int c = id >> 3, ch = id & 7;       // c: v-local, ch: m-octet
    int v = x * 64 + c, mb = y * 64 + ch * 8;
    f16x8 hh;
#pragma unroll
    for (int i = 0; i < 8; ++i) hh[i] = t[ch * 8 + i][c];
    *(f16x8*)(db + tswz(v, mb, 16)) = hh;
  }
}

// ---- 256^2 deep-pipelined NT GEMM, 8 waves, wave tile 128x64 --------------
// All MFMAs SWAPPED: acc[mi][ni] = mfma(fb[ni], fa[mi]) -> D rows = B-rows,
// D cols = A-rows (lane: col=lane&15 -> m, row=(lane>>4)*4+r2 -> b-dim).
// OUTMODE 1: fp32 row-major, f32x4 stores (cSplit batch offsets).
// OUTMODE 2: fp16 swizzled tiles, f16x4 stores (projections, RELU).
template<bool RELU, int OUTMODE>
__global__ __launch_bounds__(512, 2) void gemm256_dp(
    const _Float16* __restrict__ A, const _Float16* __restrict__ B,
    float* __restrict__ Cf, _Float16* __restrict__ Ch,
    const int ktiles, const int ldc,
    const long aBatchTiles, const long bBatchTiles, const long cBatchElems,
    const int cTilesRow, const long cOff0, const long cOff1, const int cSplit)
{
  __shared__ _Float16 sA[4][8192];   // 256 rows x 32 k per buf (16 KB)
  __shared__ _Float16 sB[4][8192];

  const int gx = gridDim.x, gy = gridDim.y;
  long nwg = (long)gx * gy * gridDim.z;
  long bid = blockIdx.x + (long)gx * (blockIdx.y + (long)gy * blockIdx.z);
  long chunk = nwg >> 3;
  long o = (bid & 7) * chunk + (bid >> 3);
  const int bx = (int)(o % gx);
  const int by = (int)((o / gx) % gy);
  const int bz = (int)(o / ((long)gx * gy));

  const int tid = threadIdx.x;
  const int lane = tid & 63, w = tid >> 6;
  const int wm = w >> 2, wn = w & 3;            // 2 x 4 wave grid, 128x64/wave
  const int lrow = lane & 15, kg = lane >> 4;
  const int swz = (lrow >> 1) & 3;              // read-side XOR slot swizzle

  const long aT0 = (long)bz * aBatchTiles + (long)(2 * by) * ktiles;
  const long bT0 = (long)bz * bBatchTiles + (long)(2 * bx) * ktiles;
  const int NKT = ktiles;

  auto stage = [&](int kt) {
    const int buf = kt & 3;
#pragma unroll
    for (int h = 0; h < 2; ++h) {
      __builtin_amdgcn_global_load_lds(
          (const AS1 void*)(A + ((aT0 + h * ktiles + kt) << 12) + w * 512 + lane * 8),
          (AS3 void*)(&sA[buf][h * 4096 + w * 512]), 16, 0, 0);
      __builtin_amdgcn_global_load_lds(
          (const AS1 void*)(B + ((bT0 + h * ktiles + kt) << 12) + w * 512 + lane * 8),
          (AS3 void*)(&sB[buf][h * 4096 + w * 512]), 16, 0, 0);
    }
  };

  const char* aF = (const char*)&sA[0][0] + wm * 8192 + lrow * 64 + ((kg ^ swz) << 4);
  const char* bF = (const char*)&sB[0][0] + (wn >> 1) * 8192
                 + ((wn & 1) * 64 + lrow) * 64 + ((kg ^ swz) << 4);

  f32x4 acc[8][4] = {};

  stage(0); stage(1); stage(2);

  for (int kt = 0; kt < NKT; ++kt) {
    if (kt < NKT - 2)       asm volatile("s_waitcnt vmcnt(8)" ::: "memory");
    else if (kt == NKT - 2) asm volatile("s_waitcnt vmcnt(4)" ::: "memory");
    else                    asm volatile("s_waitcnt vmcnt(0)" ::: "memory");
    __builtin_amdgcn_s_barrier();
    __builtin_amdgcn_sched_barrier(0);
    const int bo = (kt & 3) * 16384;
    f16x8 fa[8], fb[4];
#pragma unroll
    for (int i = 0; i < 8; ++i) fa[i] = *(const f16x8*)(aF + bo + i * 1024);
#pragma unroll
    for (int i = 0; i < 4; ++i) fb[i] = *(const f16x8*)(bF + bo + i * 1024);
    if (kt + 3 < NKT) stage(kt + 3);
    __builtin_amdgcn_s_setprio(1);
#pragma unroll
    for (int mi = 0; mi < 8; ++mi)
#pragma unroll
      for (int ni = 0; ni < 4; ++ni)
        acc[mi][ni] = __builtin_amdgcn_mfma_f32_16x16x32_f16(fb[ni], fa[mi], acc[mi][ni], 0, 0, 0);
    __builtin_amdgcn_s_setprio(0);
  }

  const int m0 = by * 256 + wm * 128 + lrow;        // D col = lane&15
  const int b0 = bx * 256 + wn * 64 + (kg << 2);    // D row = kg*4 + r2
  if (OUTMODE == 1) {
    long cbase = cSplit ? (bz < 16 ? cOff0 + (long)bz * cBatchElems
                                   : cOff1 + (long)(bz - 16) * cBatchElems)
                        : (long)bz * cBatchElems;
    float* Cb = Cf + cbase;
#pragma unroll
    for (int mi = 0; mi < 8; ++mi)
#pragma unroll
      for (int ni = 0; ni < 4; ++ni)
        *(f32x4*)(Cb + (long)(m0 + mi * 16) * ldc + b0 + ni * 16) = acc[mi][ni];
  } else {
    _Float16* Cb = Ch + (long)bz * cBatchElems;
#pragma unroll
    for (int mi = 0; mi < 8; ++mi)
#pragma unroll
      for (int ni = 0; ni < 4; ++ni) {
        f16x4 hv;
#pragma unroll
        for (int r2 = 0; r2 < 4; ++r2) {
          float x = acc[mi][ni][r2];
          if (RELU) x = fmaxf(x, 0.0f);
          hv[r2] = (_Float16)x;
        }
        *(f16x4*)(Cb + tswz(m0 + mi * 16, b0 + ni * 16, cTilesRow)) = hv;
      }
  }
}

// ---- 128^2 deep-pipelined NT GEMM (scores), swapped f32x4 epilogue --------
__global__ __launch_bounds__(256, 2) void gemm_dp(
    const _Float16* __restrict__ Ah, const _Float16* __restrict__ B,
    float* __restrict__ Cf,
    const int ktiles, const int ldc,
    const long aBatchTiles, const long bBatchTiles, const long cBatchElems)
{
  __shared__ _Float16 sA[4][4096];
  __shared__ _Float16 sB[4][4096];

  const int gx = gridDim.x, gy = gridDim.y;
  long nwg = (long)gx * gy * gridDim.z;
  long bid = blockIdx.x + (long)gx * (blockIdx.y + (long)gy * blockIdx.z);
  long chunk = nwg >> 3;
  long o = (bid & 7) * chunk + (bid >> 3);
  const int bx = (int)(o % gx);
  const int by = (int)((o / gx) % gy);
  const int bz = (int)(o / ((long)gx * gy));

  const int tid = threadIdx.x;
  const int lane = tid & 63, w = tid >> 6;
  const int wa = w >> 1, wb = w & 1;
  const int lrow = lane & 15, kg = lane >> 4;
  const int swz = (lrow >> 1) & 3;

  const long aT0 = (long)bz * aBatchTiles + (long)by * ktiles;
  const long bT0 = (long)bz * bBatchTiles + (long)bx * ktiles;
  const int NKT = ktiles;

  auto stage = [&](int kt) {
    const int buf = kt & 3;
    const long ta = (aT0 + kt) << 12;
    const long tb = (bT0 + kt) << 12;
#pragma unroll
    for (int j = 0; j < 2; ++j) {
      __builtin_amdgcn_global_load_lds(
          (const AS1 void*)(Ah + ta + j * 2048 + w * 512 + lane * 8),
          (AS3 void*)(&sA[buf][j * 2048 + w * 512]), 16, 0, 0);
      __builtin_amdgcn_global_load_lds(
          (const AS1 void*)(B + tb + j * 2048 + w * 512 + lane * 8),
          (AS3 void*)(&sB[buf][j * 2048 + w * 512]), 16, 0, 0);
    }
  };

  const char* aF = (const char*)&sA[0][0] + (wa * 64 + lrow) * 64 + ((kg ^ swz) << 4);
  const char* bF = (const char*)&sB[0][0] + (wb * 64 + lrow) * 64 + ((kg ^ swz) << 4);

  f32x4 acc[4][4] = {};

  stage(0); stage(1); stage(2);

  for (int kt = 0; kt < NKT; ++kt) {
    if (kt < NKT - 2)       asm volatile("s_waitcnt vmcnt(8)" ::: "memory");
    else if (kt == NKT - 2) asm volatile("s_waitcnt vmcnt(4)" ::: "memory");
    else                    asm volatile("s_waitcnt vmcnt(0)" ::: "memory");
    __builtin_amdgcn_s_barrier();
    __builtin_amdgcn_sched_barrier(0);
    const int bo = (kt & 3) * 8192;
    f16x8 fa[4], fb[4];
#pragma unroll
    for (int i = 0; i < 4; ++i) fa[i] = *(const f16x8*)(aF + bo + i * 1024);
#pragma unroll
    for (int i = 0; i < 4; ++i) fb[i] = *(const f16x8*)(bF + bo + i * 1024);
    if (kt + 3 < NKT) stage(kt + 3);
    __builtin_amdgcn_s_setprio(1);
#pragma unroll
    for (int mi = 0; mi < 4; ++mi)
#pragma unroll
      for (int ni = 0; ni < 4; ++ni)
        acc[mi][ni] = __builtin_amdgcn_mfma_f32_16x16x32_f16(fb[ni], fa[mi], acc[mi][ni], 0, 0, 0);
    __builtin_amdgcn_s_setprio(0);
  }

  float* Cb = Cf + (long)bz * cBatchElems;
  const int m0 = by * 128 + wa * 64 + lrow;         // D col
  const int n0 = bx * 128 + wb * 64 + (kg << 2);    // D row (4 consecutive n)
#pragma unroll
  for (int mi = 0; mi < 4; ++mi)
#pragma unroll
    for (int ni = 0; ni < 4; ++ni)
      *(f32x4*)(Cb + (long)(m0 + mi * 16) * ldc + n0 + ni * 16) = acc[mi][ni];
}

// ---- row softmax: one wave per row, no LDS, no barriers -------------------
// grid 2048 x 256 threads: 4 waves/block, row = blockIdx*4 + wave.
__global__ __launch_bounds__(256) void softmax_row(
    const float* __restrict__ S, const int* __restrict__ mask, _Float16* __restrict__ W)
{
  const int tid = threadIdx.x;
  const int lane = tid & 63, wave = tid >> 6;
  const int row = blockIdx.x * 4 + wave;
  const int b = row >> 9, m = row & 511;
  const float* Sr = S + (long)row * 512 + lane * 8;
  const int* mr = mask + (long)b * 512 + lane * 8;

  float4 f0 = *(const float4*)(Sr);
  float4 f1 = *(const float4*)(Sr + 4);
  int4 m0 = *(const int4*)(mr);
  int4 m1 = *(const int4*)(mr + 4);
  float v[8];
  v[0] = m0.x ? f0.x : -1e30f; v[1] = m0.y ? f0.y : -1e30f;
  v[2] = m0.z ? f0.z : -1e30f; v[3] = m0.w ? f0.w : -1e30f;
  v[4] = m1.x ? f1.x : -1e30f; v[5] = m1.y ? f1.y : -1e30f;
  v[6] = m1.z ? f1.z : -1e30f; v[7] = m1.w ? f1.w : -1e30f;

  float mx = v[0];
#pragma unroll
  for (int j = 1; j < 8; ++j) mx = fmaxf(mx, v[j]);
#pragma unroll
  for (int of = 32; of >= 1; of >>= 1) mx = fmaxf(mx, __shfl_xor(mx, of, 64));

  float e[8], sm = 0.0f;
#pragma unroll
  for (int j = 0; j < 8; ++j) { e[j] = __expf(v[j] - mx); sm += e[j]; }
#pragma unroll
  for (int of = 32; of >= 1; of >>= 1) sm += __shfl_xor(sm, of, 64);
  float inv = 1.0f / sm;

  f16x8 hv;
#pragma unroll
  for (int j = 0; j < 8; ++j) hv[j] = (_Float16)(e[j] * inv);
  _Float16* Wb = W + (long)b * 262144;
  *(f16x8*)(Wb + tswz(m, lane * 8, 16)) = hv;   // contiguous 16B (k&7 spans 0..7)
}

// ---- column softmax: wq[b][n][m] = softmax_m(s[b][m][n]), float4 loads ----
__global__ __launch_bounds__(256) void softmax_col(
    const float* __restrict__ S, const int* __restrict__ mask, _Float16* __restrict__ W)
{
  __shared__ float ldsT[32][513];
  const int n0 = blockIdx.x * 32, b = blockIdx.y;
  const float* Sb = S + (long)b * 262144;
  const int* mr = mask + (long)b * 512;
  const int tid = threadIdx.x;
  const int lane = tid & 63, w = tid >> 6;

  for (int it = 0; it < 16; ++it) {
    int m = it * 32 + (tid >> 3);
    int c4 = (tid & 7) << 2;
    float4 f = *(const float4*)(Sb + (long)m * 512 + n0 + c4);
    bool ok = mr[m] != 0;
    ldsT[c4 + 0][m] = ok ? f.x : -1e30f;
    ldsT[c4 + 1][m] = ok ? f.y : -1e30f;
    ldsT[c4 + 2][m] = ok ? f.z : -1e30f;
    ldsT[c4 + 3][m] = ok ? f.w : -1e30f;
  }
  __syncthreads();

  _Float16* Wb = W + (long)b * 262144;
#pragma unroll
  for (int cc = 0; cc < 8; ++cc) {
    int col = w * 8 + cc;
    float v[8];
#pragma unroll
    for (int j = 0; j < 8; ++j) v[j] = ldsT[col][lane + 64 * j];
    float mx = v[0];
#pragma unroll
    for (int j = 1; j < 8; ++j) mx = fmaxf(mx, v[j]);
#pragma unroll
    for (int of = 32; of >= 1; of >>= 1) mx = fmaxf(mx, __shfl_xor(mx, of, 64));
    float e[8], sm = 0.0f;
#pragma unroll
    for (int j = 0; j < 8; ++j) { e[j] = __expf(v[j] - mx); sm += e[j]; }
#pragma unroll
    for (int of = 32; of >= 1; of >>= 1) sm += __shfl_xor(sm, of, 64);
    float inv = 1.0f / sm;
    int n = n0 + col;
#pragma unroll
    for (int j = 0; j < 8; ++j)
      Wb[tswz(n, lane + 64 * j, 16)] = (_Float16)(e[j] * inv);
  }
}

extern "C" void kernel_launch(void* const* d_in, const int* in_sizes, int n_in,
                              void* d_out, int out_size, void* d_ws, size_t ws_size,
                              hipStream_t stream) {
  const float* q = (const float*)d_in[0];
  const float* p = (const float*)d_in[1];
  const int* q_mask = (const int*)d_in[2];
  const int* p_mask = (const int*)d_in[3];
  const float* W1 = (const float*)d_in[4];
  const float* W2 = (const float*)d_in[5];
  float* out = (float*)d_out;   // [out_p | out_q]

  char* ws = (char*)d_ws;
  const size_t MB = 1048576;
  _Float16* W1h = (_Float16*)(ws + 0 * MB);    // W2h contiguous at +2MB
  _Float16* qh  = (_Float16*)(ws + 4 * MB);    // ph contiguous at +16MB
  _Float16* sqh = (_Float16*)(ws + 36 * MB);   // sph contiguous at +16MB
  float*    s   = (float*)(ws + 68 * MB);      // fresh region (qh stays alive)
  _Float16* pT  = (_Float16*)(ws + 36 * MB);   // over sqh/sph after scores
  _Float16* wp  = (_Float16*)(ws + 4 * MB);    // over qh after prep_xT2
  _Float16* wq  = (_Float16*)(ws + 12 * MB);

  dim3 blk(256);

  // 1) fp16 conversions into swizzled tiles (q, p, W1|W2 in one kernel)
  prep_all<<<9216, blk, 0, stream>>>(q, p, W1, W2, qh, W1h);

  // 2) merged projections, 256^2 (z=0: q@W1 -> sqh, z=1: p@W2 -> sph)
  gemm256_dp<true, 2><<<dim3(4, 32, 2), dim3(512), 0, stream>>>(
      qh, W1h, nullptr, sqh,
      /*ktiles=*/32, /*ldc=*/0,
      /*aBatchTiles=*/2048, /*bBatchTiles=*/256, /*cBatchElems=*/8388608L,
      /*cTilesRow=*/32, 0, 0, 0);

  // 3) scores: s[b] = s_q[b] @ s_p[b]^T, 128^2 swapped f32x4 epilogue
  gemm_dp<<<dim3(4, 4, 16), blk, 0, stream>>>(
      sqh, (_Float16*)(ws + 52 * MB), s, /*ktiles=*/32, /*ldc=*/512,
      /*aBatchTiles=*/128, /*bBatchTiles=*/128, /*cBatchElems=*/262144L);

  // 4) transposed fp16 copies of p, q from the fp16 tiles (over dead sqh/sph)
  prep_xT2<<<dim3(16, 8, 32), blk, 0, stream>>>(qh, pT);

  // 5) softmaxes (write over dead qh region)
  softmax_row<<<2048, blk, 0, stream>>>(s, p_mask, wp);
  softmax_col<<<dim3(16, 16), blk, 0, stream>>>(s, q_mask, wq);

  // 6) merged outputs, 256^2: z<16: out_q = wp@pT^T; z>=16: out_p = wq@qT^T
  gemm256_dp<false, 1><<<dim3(4, 2, 32), dim3(512), 0, stream>>>(
      wp, pT, out, nullptr,
      /*ktiles=*/16, /*ldc=*/1024,
      /*aBatchTiles=*/64, /*bBatchTiles=*/128, /*cBatchElems=*/524288L,
      0, /*cOff0=*/8388608L, /*cOff1=*/0L, /*cSplit=*/1);
}